// Round 1
// baseline (231.146 us; speedup 1.0000x reference)
//
#include <hip/hip_runtime.h>
#include <math.h>

#define BATCH 8
#define NOBJ  32
#define NANCH 16384
#define NTOT  (BATCH * NANCH)   // 131072

#define HIST 65536
// ws layout in 4-byte words:
// [0] n_pos (int)  [1] n_neg (int)  [2] sum_box (f32)  [3] sum_pos (f32)
// [4] wsum_pos (f32)  [5] k (int)  [6] hb (int)  [7] r (int)
// [8] sum_hi (f32)  [9] mode (int, 1=done)  [10] sum_neg (f32)
#define OFF_HI_CNT 16
#define OFF_HI_SUM (16 + HIST)
#define OFF_LO_CNT (16 + 2 * HIST)
#define OFF_LO_SUM (16 + 3 * HIST)
#define OFF_BITS   (16 + 4 * HIST)
// total ws words: 16 + 4*65536 + 131072 = 393232 (~1.5 MB)

__device__ __forceinline__ float smooth_l1f(float d) {
    float ad = fabsf(d);
    return ad < 1.0f ? 0.5f * ad * ad : ad - 0.5f;
}

__global__ __launch_bounds__(256) void dl_main(
    const float* __restrict__ pred_boxes,
    const float* __restrict__ pred_classes,
    const float* __restrict__ true_boxes,
    const int*   __restrict__ true_classes,
    const float* __restrict__ anchors,
    unsigned int* __restrict__ ws)
{
    __shared__ float s_tb[NOBJ * 4];
    __shared__ int   s_tc[NOBJ];
    int idx = blockIdx.x * 256 + threadIdx.x;   // blocks never straddle images (16384 % 256 == 0)
    int b = idx >> 14;
    int a = idx & (NANCH - 1);
    if (threadIdx.x < NOBJ * 4) s_tb[threadIdx.x] = true_boxes[b * NOBJ * 4 + threadIdx.x];
    if (threadIdx.x < NOBJ)     s_tc[threadIdx.x] = true_classes[b * NOBJ + threadIdx.x];
    __syncthreads();

    float4 anc = reinterpret_cast<const float4*>(anchors)[a];   // (cx, cy, w, h)
    float ax1 = anc.x - anc.z * 0.5f;
    float ay1 = anc.y - anc.w * 0.5f;
    float ax2 = anc.x + anc.z * 0.5f;
    float ay2 = anc.y + anc.w * 0.5f;
    float area_a = (ax2 - ax1) * (ay2 - ay1);

    float ov[NOBJ];
    float best = -3.402823466e38f;
#pragma unroll
    for (int o = 0; o < NOBJ; ++o) {
        float v;
        if (s_tc[o] < 0) {
            v = -1.0f;   // padded slot: reference masks overlap to -1
        } else {
            float bx1 = s_tb[o * 4 + 0], by1 = s_tb[o * 4 + 1];
            float bx2 = s_tb[o * 4 + 2], by2 = s_tb[o * 4 + 3];
            float ltx = fmaxf(ax1, bx1), lty = fmaxf(ay1, by1);
            float rbx = fminf(ax2, bx2), rby = fminf(ay2, by2);
            float w = fmaxf(rbx - ltx, 0.0f), h = fmaxf(rby - lty, 0.0f);
            float inter = w * h;
            float area_b = (bx2 - bx1) * (by2 - by1);
            v = inter / (area_a + area_b - inter);
        }
        ov[o] = v;
        best = fmaxf(best, v);
    }

    // log-softmax over 2 classes
    float2 pc = reinterpret_cast<const float2*>(pred_classes)[idx];
    float mx = fmaxf(pc.x, pc.y);
    float lse = mx + logf(expf(pc.x - mx) + expf(pc.y - mx));
    float l0 = pc.x - lse;
    float l1 = pc.y - lse;

    // negative anchor: best gt overlap < 0.5
    unsigned bits = 0xFFFFFFFFu;   // marker: not negative
    if (best < 0.5f) {
        float nce = -l0;           // > 0, so bit pattern orders like unsigned
        bits = __float_as_uint(nce);
        atomicAdd((int*)(ws + 1), 1);
        atomicAdd(ws + OFF_HI_CNT + (bits >> 16), 1u);
        atomicAdd((float*)(ws + OFF_HI_SUM) + (bits >> 16), nce);
    }
    ws[OFF_BITS + idx] = bits;

    // positives: per (o): |best - ov| < 1e-6 and ov > 0.5
    float4 pb = reinterpret_cast<const float4*>(pred_boxes)[idx];
    int npos = 0; float boxs = 0.f, poss = 0.f, wsum = 0.f;
#pragma unroll
    for (int o = 0; o < NOBJ; ++o) {
        float v = ov[o];
        if (fabsf(best - v) < 1e-6f && v > 0.5f) {
            ++npos;
            float bx1 = s_tb[o * 4 + 0], by1 = s_tb[o * 4 + 1];
            float bx2 = s_tb[o * 4 + 2], by2 = s_tb[o * 4 + 3];
            // encode(matched=corner gt, prior=center-size anchor), VAR0=0.1, VAR1=0.2
            float gcx = ((bx1 + bx2) * 0.5f - anc.x) / (0.1f * anc.z);
            float gcy = ((by1 + by2) * 0.5f - anc.y) / (0.1f * anc.w);
            float gw  = logf((bx2 - bx1) / anc.z) / 0.2f;
            float gh  = logf((by2 - by1) / anc.w) / 0.2f;
            boxs += smooth_l1f(pb.x - gcx) + smooth_l1f(pb.y - gcy)
                  + smooth_l1f(pb.z - gw)  + smooth_l1f(pb.w - gh);
            int c = s_tc[o];                 // >= 0 here (pad can't be positive)
            float w = (c == 1) ? 4.0f : 1.0f;
            poss += w * ((c == 1) ? -l1 : -l0);
            wsum += w;
        }
    }
    if (npos) {
        atomicAdd((int*)(ws + 0), npos);
        atomicAdd((float*)(ws + 2), boxs);
        atomicAdd((float*)(ws + 3), poss);
        atomicAdd((float*)(ws + 4), wsum);
    }
}

// scan hi-16 histogram from the top; find cutoff bucket for top-k
__global__ __launch_bounds__(256) void dl_sel_hi(unsigned int* __restrict__ ws)
{
    __shared__ int   s_cnt[256];
    __shared__ float s_sum[256];
    int t = threadIdx.x;
    const unsigned* hc = ws + OFF_HI_CNT;
    const float*    hs = (const float*)(ws + OFF_HI_SUM);
    int c = 0; float s = 0.f;
    for (int i = 0; i < 256; ++i) { c += (int)hc[t * 256 + i]; s += hs[t * 256 + i]; }
    s_cnt[t] = c; s_sum[t] = s;
    __syncthreads();
    if (t == 0) {
        int n_pos = ((int*)ws)[0];
        int n_neg = ((int*)ws)[1];
        long long k10 = (long long)10 * (long long)n_pos;
        int k = (int)((k10 < (long long)n_neg) ? k10 : (long long)n_neg);
        ((int*)ws)[5] = k;
        if (k == 0) { ((int*)ws)[9] = 1; ((float*)ws)[10] = 0.0f; return; }
        int cum = 0; float sumhi = 0.f; int strip = 0;
        for (int i = 255; i >= 0; --i) {
            if (cum + s_cnt[i] >= k) { strip = i; break; }
            cum += s_cnt[i]; sumhi += s_sum[i];
        }
        for (int bkt = strip * 256 + 255; bkt >= strip * 256; --bkt) {
            int cb = (int)hc[bkt];
            if (cum + cb >= k) {
                int r = k - cum;
                if (r == cb) {      // whole bucket taken — done, no lo pass
                    ((int*)ws)[9] = 1; ((float*)ws)[10] = sumhi + hs[bkt];
                } else {
                    ((int*)ws)[9] = 0; ((int*)ws)[6] = bkt;
                    ((int*)ws)[7] = r; ((float*)ws)[8] = sumhi;
                }
                return;
            }
            cum += cb; sumhi += hs[bkt];
        }
    }
}

// lo-16 histogram of values inside the cutoff hi bucket
__global__ __launch_bounds__(256) void dl_lo_hist(unsigned int* __restrict__ ws)
{
    if (((const volatile int*)ws)[9] == 1) return;
    int hb = ((const int*)ws)[6];
    int idx = blockIdx.x * 256 + threadIdx.x;
    unsigned bits = ws[OFF_BITS + idx];
    if ((int)(bits >> 16) == hb) {   // 0xFFFF marker never matches (values are finite positive)
        atomicAdd(ws + OFF_LO_CNT + (bits & 0xFFFFu), 1u);
        atomicAdd((float*)(ws + OFF_LO_SUM) + (bits & 0xFFFFu), __uint_as_float(bits));
    }
}

__global__ __launch_bounds__(256) void dl_final(unsigned int* __restrict__ ws,
                                                float* __restrict__ out)
{
    __shared__ int   s_cnt[256];
    __shared__ float s_sum[256];
    int t = threadIdx.x;
    const unsigned* lc = ws + OFF_LO_CNT;
    const float*    ls = (const float*)(ws + OFF_LO_SUM);
    int c = 0; float s = 0.f;
    for (int i = 0; i < 256; ++i) { c += (int)lc[t * 256 + i]; s += ls[t * 256 + i]; }
    s_cnt[t] = c; s_sum[t] = s;
    __syncthreads();
    if (t == 0) {
        int n_pos = ((int*)ws)[0];
        int k     = ((int*)ws)[5];
        float sum_neg;
        if (((int*)ws)[9] == 1) {
            sum_neg = ((float*)ws)[10];
        } else {
            int hb = ((int*)ws)[6];
            int r  = ((int*)ws)[7];
            float acc = ((float*)ws)[8];
            int cum = 0; int strip = 0;
            for (int i = 255; i >= 0; --i) {
                if (cum + s_cnt[i] >= r) { strip = i; break; }
                cum += s_cnt[i]; acc += s_sum[i];
            }
            for (int bkt = strip * 256 + 255; bkt >= strip * 256; --bkt) {
                int cb = (int)lc[bkt];
                if (cum + cb >= r) {
                    int r2 = r - cum;   // values in this bucket share one exact bit pattern
                    float v = __uint_as_float(((unsigned)hb << 16) | (unsigned)bkt);
                    acc += (float)r2 * v;
                    break;
                }
                cum += cb; acc += ls[bkt];
            }
            sum_neg = acc;
        }
        float denom = (float)(n_pos > 1 ? n_pos : 1);
        float box_loss = ((float*)ws)[2] / denom;
        float cls_loss = 10.0f * (((float*)ws)[3] + sum_neg)
                       / fmaxf(((float*)ws)[4] + (float)k, 1e-6f) / denom;
        out[0] = box_loss;
        out[1] = cls_loss;
        out[2] = box_loss + cls_loss;
    }
}

extern "C" void kernel_launch(void* const* d_in, const int* in_sizes, int n_in,
                              void* d_out, int out_size, void* d_ws, size_t ws_size,
                              hipStream_t stream)
{
    const float* pred_boxes   = (const float*)d_in[0];
    const float* pred_classes = (const float*)d_in[1];
    const float* true_boxes   = (const float*)d_in[2];
    const int*   true_classes = (const int*)d_in[3];
    const float* anchors      = (const float*)d_in[4];
    unsigned int* ws = (unsigned int*)d_ws;

    // zero scalars + both histograms (neg-bits array is fully rewritten each call)
    hipMemsetAsync(ws, 0, (size_t)OFF_BITS * sizeof(unsigned int), stream);

    dl_main<<<NTOT / 256, 256, 0, stream>>>(pred_boxes, pred_classes, true_boxes,
                                            true_classes, anchors, ws);
    dl_sel_hi<<<1, 256, 0, stream>>>(ws);
    dl_lo_hist<<<NTOT / 256, 256, 0, stream>>>(ws);
    dl_final<<<1, 256, 0, stream>>>(ws, (float*)d_out);
}

// Round 2
// 55.315 us; speedup vs baseline: 4.1787x; 4.1787x over previous
//
#include <hip/hip_runtime.h>
#include <math.h>

#define BATCH 8
#define NOBJ  32
#define NANCH 16384
#define NTOT  (BATCH * NANCH)   // 131072

// ---- ws word layout ----
// scalars
#define S_NPOS 0   // int
#define S_NNEG 1   // int
#define S_BOX  2   // f32 sum
#define S_POS  3   // f32 sum
#define S_WSUM 4   // f32 sum
#define S_K    5   // int
#define S_B1   6   // int (level-1 bucket)
#define S_R    7   // int remaining target within current level
#define S_ACC  8   // f32 sum of fully-taken buckets so far
#define S_DONE 9   // int
#define S_SNEG 10  // f32 final negative sum (when done early)
#define S_HB   11  // int combined (b1<<12)|b2 prefix for level 3

#define OFF_SLOTS 64                       // 512 blocks * 8 words
#define OFF_H1C   (OFF_SLOTS + 512 * 8)    // 2048 cnt
#define OFF_H1S   (OFF_H1C + 2048)         // 2048 f32 sum
#define OFF_H2C   (OFF_H1S + 2048)         // 4096 cnt
#define OFF_H2S   (OFF_H2C + 4096)         // 4096 f32 sum
#define OFF_H3C   (OFF_H2S + 4096)         // 256 cnt
#define OFF_ZERO_END (OFF_H3C + 256)       // words to memset
#define OFF_BITS  OFF_ZERO_END             // 131072 words, fully rewritten
// total: OFF_BITS + 131072 words ~= 578 KB (ws proven >= 1.57 MB in R0)

__device__ __forceinline__ float smooth_l1f(float d) {
    float ad = fabsf(d);
    return ad < 1.0f ? 0.5f * ad * ad : ad - 0.5f;
}

__global__ __launch_bounds__(256) void dl_main(
    const float* __restrict__ pred_boxes,
    const float* __restrict__ pred_classes,
    const float* __restrict__ true_boxes,
    const int*   __restrict__ true_classes,
    const float* __restrict__ anchors,
    unsigned int* __restrict__ ws)
{
    __shared__ float s_tb[NOBJ * 4];
    __shared__ int   s_tc[NOBJ];
    __shared__ int   s_ri[4][2];
    __shared__ float s_rf[4][3];
    int idx = blockIdx.x * 256 + threadIdx.x;   // 16384 % 256 == 0: blocks never straddle images
    int b = idx >> 14;
    int a = idx & (NANCH - 1);
    if (threadIdx.x < NOBJ * 4) s_tb[threadIdx.x] = true_boxes[b * NOBJ * 4 + threadIdx.x];
    if (threadIdx.x < NOBJ)     s_tc[threadIdx.x] = true_classes[b * NOBJ + threadIdx.x];
    __syncthreads();

    float4 anc = reinterpret_cast<const float4*>(anchors)[a];   // (cx, cy, w, h)
    float ax1 = anc.x - anc.z * 0.5f;
    float ay1 = anc.y - anc.w * 0.5f;
    float ax2 = anc.x + anc.z * 0.5f;
    float ay2 = anc.y + anc.w * 0.5f;
    float area_a = (ax2 - ax1) * (ay2 - ay1);

    float ov[NOBJ];
    float best = -3.402823466e38f;
#pragma unroll
    for (int o = 0; o < NOBJ; ++o) {
        float v;
        if (s_tc[o] < 0) {
            v = -1.0f;   // reference masks padded slots' overlap to -1
        } else {
            float bx1 = s_tb[o * 4 + 0], by1 = s_tb[o * 4 + 1];
            float bx2 = s_tb[o * 4 + 2], by2 = s_tb[o * 4 + 3];
            float ltx = fmaxf(ax1, bx1), lty = fmaxf(ay1, by1);
            float rbx = fminf(ax2, bx2), rby = fminf(ay2, by2);
            float w = fmaxf(rbx - ltx, 0.0f), h = fmaxf(rby - lty, 0.0f);
            float inter = w * h;
            float area_b = (bx2 - bx1) * (by2 - by1);
            v = inter / (area_a + area_b - inter);
        }
        ov[o] = v;
        best = fmaxf(best, v);
    }

    // log-softmax over 2 classes
    float2 pc = reinterpret_cast<const float2*>(pred_classes)[idx];
    float mx = fmaxf(pc.x, pc.y);
    float lse = mx + logf(expf(pc.x - mx) + expf(pc.y - mx));
    float l0 = pc.x - lse;
    float l1 = pc.y - lse;

    // negative anchor: best gt overlap < 0.5. nce > 0 so float bits order as uint.
    unsigned bits = 0xFFFFFFFFu;   // marker: not negative
    int isneg = 0;
    if (best < 0.5f) { bits = __float_as_uint(-l0); isneg = 1; }
    ws[OFF_BITS + idx] = bits;

    // positives: per o, |best - ov| < 1e-6 and ov > 0.5
    float4 pb = reinterpret_cast<const float4*>(pred_boxes)[idx];
    int npos = 0; float boxs = 0.f, poss = 0.f, wsum = 0.f;
#pragma unroll
    for (int o = 0; o < NOBJ; ++o) {
        float v = ov[o];
        if (fabsf(best - v) < 1e-6f && v > 0.5f) {
            ++npos;
            float bx1 = s_tb[o * 4 + 0], by1 = s_tb[o * 4 + 1];
            float bx2 = s_tb[o * 4 + 2], by2 = s_tb[o * 4 + 3];
            float gcx = ((bx1 + bx2) * 0.5f - anc.x) / (0.1f * anc.z);
            float gcy = ((by1 + by2) * 0.5f - anc.y) / (0.1f * anc.w);
            float gw  = logf((bx2 - bx1) / anc.z) / 0.2f;
            float gh  = logf((by2 - by1) / anc.w) / 0.2f;
            boxs += smooth_l1f(pb.x - gcx) + smooth_l1f(pb.y - gcy)
                  + smooth_l1f(pb.z - gw)  + smooth_l1f(pb.w - gh);
            int c = s_tc[o];
            float w = (c == 1) ? 4.0f : 1.0f;
            poss += w * ((c == 1) ? -l1 : -l0);
            wsum += w;
        }
    }

    // block reduction -> private slot (NO global atomics)
    int ip = npos, ng = isneg;
    float fb = boxs, fp = poss, fw = wsum;
#pragma unroll
    for (int off = 32; off; off >>= 1) {
        ip += __shfl_down(ip, off);
        ng += __shfl_down(ng, off);
        fb += __shfl_down(fb, off);
        fp += __shfl_down(fp, off);
        fw += __shfl_down(fw, off);
    }
    int wid = threadIdx.x >> 6, lane = threadIdx.x & 63;
    if (lane == 0) {
        s_ri[wid][0] = ip; s_ri[wid][1] = ng;
        s_rf[wid][0] = fb; s_rf[wid][1] = fp; s_rf[wid][2] = fw;
    }
    __syncthreads();
    if (threadIdx.x == 0) {
        int tp = 0, tn = 0; float t2 = 0.f, t3 = 0.f, t4 = 0.f;
        for (int wv = 0; wv < 4; ++wv) {
            tp += s_ri[wv][0]; tn += s_ri[wv][1];
            t2 += s_rf[wv][0]; t3 += s_rf[wv][1]; t4 += s_rf[wv][2];
        }
        int base = OFF_SLOTS + blockIdx.x * 8;
        ((int*)ws)[base + 0] = tp;
        ((int*)ws)[base + 1] = tn;
        ((float*)ws)[base + 2] = t2;
        ((float*)ws)[base + 3] = t3;
        ((float*)ws)[base + 4] = t4;
    }
}

// level-1 histogram (bits>>20, 2048 buckets), LDS-privatized, 128 blocks
__global__ __launch_bounds__(256) void dl_hist1(unsigned int* __restrict__ ws)
{
    __shared__ unsigned hc[2048];
    __shared__ float    hs[2048];
    for (int i = threadIdx.x; i < 2048; i += 256) { hc[i] = 0u; hs[i] = 0.f; }
    __syncthreads();
    int base = blockIdx.x * 1024 + threadIdx.x;
#pragma unroll
    for (int j = 0; j < 4; ++j) {
        unsigned bits = ws[OFF_BITS + base + j * 256];
        if (bits != 0xFFFFFFFFu) {
            atomicAdd(&hc[bits >> 20], 1u);
            atomicAdd(&hs[bits >> 20], __uint_as_float(bits));
        }
    }
    __syncthreads();
    for (int i = threadIdx.x; i < 2048; i += 256) {
        unsigned c = hc[i];
        if (c) {
            atomicAdd(ws + OFF_H1C + i, c);
            atomicAdd((float*)(ws + OFF_H1S) + i, hs[i]);
        }
    }
}

// reduce slots, compute k, scan level-1 histogram top-down
__global__ __launch_bounds__(256) void dl_sel1(unsigned int* __restrict__ ws)
{
    __shared__ int   s_ri[4][2];
    __shared__ float s_rf[4][3];
    __shared__ int   s_c[256];
    __shared__ float s_s[256];
    int t = threadIdx.x;
    int ip = 0, ng = 0; float fb = 0.f, fp = 0.f, fw = 0.f;
    for (int s = t; s < 512; s += 256) {
        int base = OFF_SLOTS + s * 8;
        ip += ((const int*)ws)[base + 0];
        ng += ((const int*)ws)[base + 1];
        fb += ((const float*)ws)[base + 2];
        fp += ((const float*)ws)[base + 3];
        fw += ((const float*)ws)[base + 4];
    }
#pragma unroll
    for (int off = 32; off; off >>= 1) {
        ip += __shfl_down(ip, off);
        ng += __shfl_down(ng, off);
        fb += __shfl_down(fb, off);
        fp += __shfl_down(fp, off);
        fw += __shfl_down(fw, off);
    }
    int wid = t >> 6, lane = t & 63;
    if (lane == 0) {
        s_ri[wid][0] = ip; s_ri[wid][1] = ng;
        s_rf[wid][0] = fb; s_rf[wid][1] = fp; s_rf[wid][2] = fw;
    }
    // strip partials: thread t owns buckets [t*8, t*8+8)
    int c = 0; float sm = 0.f;
    for (int i = 0; i < 8; ++i) {
        c  += (int)ws[OFF_H1C + t * 8 + i];
        sm += ((const float*)(ws + OFF_H1S))[t * 8 + i];
    }
    s_c[t] = c; s_s[t] = sm;
    __syncthreads();
    if (t == 0) {
        int n_pos = 0, n_neg = 0; float t2 = 0.f, t3 = 0.f, t4 = 0.f;
        for (int wv = 0; wv < 4; ++wv) {
            n_pos += s_ri[wv][0]; n_neg += s_ri[wv][1];
            t2 += s_rf[wv][0]; t3 += s_rf[wv][1]; t4 += s_rf[wv][2];
        }
        ((int*)ws)[S_NPOS] = n_pos;
        ((int*)ws)[S_NNEG] = n_neg;
        ((float*)ws)[S_BOX]  = t2;
        ((float*)ws)[S_POS]  = t3;
        ((float*)ws)[S_WSUM] = t4;
        long long k10 = 10LL * (long long)n_pos;
        int k = (int)((k10 < (long long)n_neg) ? k10 : (long long)n_neg);
        ((int*)ws)[S_K] = k;
        if (k == 0) { ((int*)ws)[S_DONE] = 1; ((float*)ws)[S_SNEG] = 0.f; return; }
        int cum = 0; float acc = 0.f; int strip = 255;
        while (strip >= 0 && cum + s_c[strip] < k) { cum += s_c[strip]; acc += s_s[strip]; --strip; }
        for (int i = strip * 8 + 7; i >= strip * 8; --i) {
            int cb = (int)ws[OFF_H1C + i];
            if (cum + cb >= k) {
                int r = k - cum;
                if (r == cb) {
                    ((int*)ws)[S_DONE] = 1;
                    ((float*)ws)[S_SNEG] = acc + ((const float*)(ws + OFF_H1S))[i];
                } else {
                    ((int*)ws)[S_DONE] = 0;
                    ((int*)ws)[S_B1] = i;
                    ((int*)ws)[S_R] = r;
                    ((float*)ws)[S_ACC] = acc;
                }
                return;
            }
            cum += cb; acc += ((const float*)(ws + OFF_H1S))[i];
        }
    }
}

// level-2 histogram ((bits>>8)&0xFFF) within bucket b1, LDS-privatized
__global__ __launch_bounds__(256) void dl_hist2(unsigned int* __restrict__ ws)
{
    if (((const volatile int*)ws)[S_DONE]) return;
    int b1 = ((const volatile int*)ws)[S_B1];
    __shared__ unsigned hc[4096];
    __shared__ float    hs[4096];
    for (int i = threadIdx.x; i < 4096; i += 256) { hc[i] = 0u; hs[i] = 0.f; }
    __syncthreads();
    int base = blockIdx.x * 1024 + threadIdx.x;
#pragma unroll
    for (int j = 0; j < 4; ++j) {
        unsigned bits = ws[OFF_BITS + base + j * 256];
        if (bits != 0xFFFFFFFFu && (int)(bits >> 20) == b1) {
            atomicAdd(&hc[(bits >> 8) & 0xFFFu], 1u);
            atomicAdd(&hs[(bits >> 8) & 0xFFFu], __uint_as_float(bits));
        }
    }
    __syncthreads();
    for (int i = threadIdx.x; i < 4096; i += 256) {
        unsigned c = hc[i];
        if (c) {
            atomicAdd(ws + OFF_H2C + i, c);
            atomicAdd((float*)(ws + OFF_H2S) + i, hs[i]);
        }
    }
}

__global__ __launch_bounds__(256) void dl_sel2(unsigned int* __restrict__ ws)
{
    if (((const volatile int*)ws)[S_DONE]) return;
    __shared__ int   s_c[256];
    __shared__ float s_s[256];
    int t = threadIdx.x;
    int c = 0; float sm = 0.f;
    for (int i = 0; i < 16; ++i) {
        c  += (int)ws[OFF_H2C + t * 16 + i];
        sm += ((const float*)(ws + OFF_H2S))[t * 16 + i];
    }
    s_c[t] = c; s_s[t] = sm;
    __syncthreads();
    if (t == 0) {
        int r = ((const int*)ws)[S_R];
        int b1 = ((const int*)ws)[S_B1];
        float acc = ((const float*)ws)[S_ACC];
        int cum = 0; int strip = 255;
        while (strip >= 0 && cum + s_c[strip] < r) { cum += s_c[strip]; acc += s_s[strip]; --strip; }
        for (int i = strip * 16 + 15; i >= strip * 16; --i) {
            int cb = (int)ws[OFF_H2C + i];
            if (cum + cb >= r) {
                int r2 = r - cum;
                if (r2 == cb) {
                    ((int*)ws)[S_DONE] = 1;
                    ((float*)ws)[S_SNEG] = acc + ((const float*)(ws + OFF_H2S))[i];
                } else {
                    ((int*)ws)[S_HB] = (b1 << 12) | i;
                    ((int*)ws)[S_R] = r2;
                    ((float*)ws)[S_ACC] = acc;
                }
                return;
            }
            cum += cb; acc += ((const float*)(ws + OFF_H2S))[i];
        }
    }
}

// level-3: count-only histogram of low 8 bits within prefix (b1<<12)|b2
__global__ __launch_bounds__(256) void dl_hist3(unsigned int* __restrict__ ws)
{
    if (((const volatile int*)ws)[S_DONE]) return;
    int hb = ((const volatile int*)ws)[S_HB];
    __shared__ unsigned hc[256];
    hc[threadIdx.x] = 0u;
    __syncthreads();
    int base = blockIdx.x * 1024 + threadIdx.x;
#pragma unroll
    for (int j = 0; j < 4; ++j) {
        unsigned bits = ws[OFF_BITS + base + j * 256];
        if (bits != 0xFFFFFFFFu && (int)(bits >> 8) == hb) {
            atomicAdd(&hc[bits & 0xFFu], 1u);
        }
    }
    __syncthreads();
    unsigned c = hc[threadIdx.x];
    if (c) atomicAdd(ws + OFF_H3C + threadIdx.x, c);
}

__global__ __launch_bounds__(256) void dl_final(unsigned int* __restrict__ ws,
                                                float* __restrict__ out)
{
    __shared__ int s_c[256];
    int t = threadIdx.x;
    s_c[t] = (int)ws[OFF_H3C + t];   // parallel load (garbage if done; unused then)
    __syncthreads();
    if (t == 0) {
        float sum_neg;
        if (((const int*)ws)[S_DONE]) {
            sum_neg = ((const float*)ws)[S_SNEG];
        } else {
            int r = ((const int*)ws)[S_R];
            unsigned hb = (unsigned)((const int*)ws)[S_HB];
            float acc = ((const float*)ws)[S_ACC];
            int cum = 0;
            for (int i = 255; i >= 0; --i) {
                int cb = s_c[i];
                float v = __uint_as_float((hb << 8) | (unsigned)i);
                if (cum + cb >= r) { acc += (float)(r - cum) * v; break; }
                cum += cb; acc += (float)cb * v;
            }
            sum_neg = acc;
        }
        int n_pos = ((const int*)ws)[S_NPOS];
        int k     = ((const int*)ws)[S_K];
        float denom = (float)(n_pos > 1 ? n_pos : 1);
        float box_loss = ((const float*)ws)[S_BOX] / denom;
        float cls_loss = 10.0f * (((const float*)ws)[S_POS] + sum_neg)
                       / fmaxf(((const float*)ws)[S_WSUM] + (float)k, 1e-6f) / denom;
        out[0] = box_loss;
        out[1] = cls_loss;
        out[2] = box_loss + cls_loss;
    }
}

extern "C" void kernel_launch(void* const* d_in, const int* in_sizes, int n_in,
                              void* d_out, int out_size, void* d_ws, size_t ws_size,
                              hipStream_t stream)
{
    const float* pred_boxes   = (const float*)d_in[0];
    const float* pred_classes = (const float*)d_in[1];
    const float* true_boxes   = (const float*)d_in[2];
    const int*   true_classes = (const int*)d_in[3];
    const float* anchors      = (const float*)d_in[4];
    unsigned int* ws = (unsigned int*)d_ws;

    hipMemsetAsync(ws, 0, (size_t)OFF_ZERO_END * sizeof(unsigned int), stream);

    dl_main<<<NTOT / 256, 256, 0, stream>>>(pred_boxes, pred_classes, true_boxes,
                                            true_classes, anchors, ws);
    dl_hist1<<<128, 256, 0, stream>>>(ws);
    dl_sel1<<<1, 256, 0, stream>>>(ws);
    dl_hist2<<<128, 256, 0, stream>>>(ws);
    dl_sel2<<<1, 256, 0, stream>>>(ws);
    dl_hist3<<<128, 256, 0, stream>>>(ws);
    dl_final<<<1, 256, 0, stream>>>(ws, (float*)d_out);
}